// Round 1
// baseline (678.967 us; speedup 1.0000x reference)
//
#include <hip/hip_runtime.h>
#include <hip/hip_bf16.h>

// Problem constants
#define Bc 2
#define Tc 2048
#define Cc 2048
#define Hc 16
#define Dc 128
#define BTc 4096
#define NQ 6144            // 3*Cc
#define EPSc 1e-5f
#define QSCALE 0.08838834764831845f   // 1/sqrt(128)

typedef __attribute__((ext_vector_type(8))) short bf16x8;
typedef __attribute__((ext_vector_type(4))) short bf16x4;
typedef __attribute__((ext_vector_type(4))) float f32x4;

__device__ __forceinline__ f32x4 mfma16(bf16x8 a, bf16x8 b, f32x4 c) {
  return __builtin_amdgcn_mfma_f32_16x16x32_bf16(a, b, c, 0, 0, 0);
}

__device__ __forceinline__ void gload16(const void* g, void* l) {
  __builtin_amdgcn_global_load_lds(
      (const __attribute__((address_space(1))) void*)g,
      (__attribute__((address_space(3))) void*)l, 16, 0, 0);
}

// ---------------- fp32 -> bf16 convert (x) ----------------
__global__ __launch_bounds__(256) void k_xconv(const float* __restrict__ x,
                                               __hip_bfloat16* __restrict__ xb) {
  size_t i = ((size_t)blockIdx.x * 256 + threadIdx.x) * 4;
  float4 v = *(const float4*)(x + i);
  union { __hip_bfloat16 h[4]; bf16x4 v4; } u;
  u.h[0] = __float2bfloat16(v.x); u.h[1] = __float2bfloat16(v.y);
  u.h[2] = __float2bfloat16(v.z); u.h[3] = __float2bfloat16(v.w);
  *(bf16x4*)(xb + i) = u.v4;
}

// ------- weight transpose+convert: W (K x N) fp32 -> Wt (N x K) bf16 -------
__global__ __launch_bounds__(256) void k_wconv(const float* __restrict__ Wq,
    const float* __restrict__ Wk, const float* __restrict__ Wv,
    const float* __restrict__ Wp, __hip_bfloat16* __restrict__ Wqkv_t,
    __hip_bfloat16* __restrict__ Wproj_t) {
  __shared__ float tile[64][65];
  int z = blockIdx.z;
  const float* src = (z == 0) ? Wq : (z == 1) ? Wk : (z == 2) ? Wv : Wp;
  __hip_bfloat16* dst = (z < 3) ? (Wqkv_t + (size_t)z * Cc * Cc) : Wproj_t;
  int k0 = blockIdx.x * 64, n0 = blockIdx.y * 64;
  int c = threadIdx.x & 63, rb = threadIdx.x >> 6;
  for (int i = 0; i < 16; i++) {
    int r = rb * 16 + i;
    tile[r][c] = src[(size_t)(k0 + r) * Cc + n0 + c];
  }
  __syncthreads();
  for (int i = 0; i < 16; i++) {
    int r = rb * 16 + i;
    dst[(size_t)(n0 + r) * Cc + k0 + c] = __float2bfloat16(tile[c][r]);
  }
}

// ---------------- bf16 GEMM, B pre-transposed (N x K), m97 structure -------
// C[m][n] = sum_k A[m][k] * Bt[n][k]
template <typename OutT>
__global__ __launch_bounds__(256) void k_gemm(const __hip_bfloat16* __restrict__ A,
    const __hip_bfloat16* __restrict__ Bt, OutT* __restrict__ Co,
    int M, int N, int K) {
  __shared__ __align__(16) __hip_bfloat16 As[128][32];
  __shared__ __align__(16) __hip_bfloat16 Bs[128][32];
  const int m0 = blockIdx.x * 128, n0 = blockIdx.y * 128;
  const int w = threadIdx.x >> 6, lane = threadIdx.x & 63;
  const int wr = w >> 1, wc = w & 1;
  const int lr = lane & 15, lg = lane >> 4;
  const int srow = lane >> 2, scolE = (lane & 3) * 8;
  f32x4 zero = {0.f, 0.f, 0.f, 0.f};
  f32x4 acc[4][4];
  for (int m = 0; m < 4; m++)
    for (int n = 0; n < 4; n++) acc[m][n] = zero;
  for (int k0 = 0; k0 < K; k0 += 32) {
    for (int q = 0; q < 2; q++) {
      int row = w * 32 + q * 16 + srow;
      gload16(A  + (size_t)(m0 + row) * K + k0 + scolE, &As[w * 32 + q * 16][0]);
      gload16(Bt + (size_t)(n0 + row) * K + k0 + scolE, &Bs[w * 32 + q * 16][0]);
    }
    __syncthreads();
    bf16x8 af[4], bfm[4];
    for (int m = 0; m < 4; m++) af[m]  = *(const bf16x8*)&As[wr * 64 + m * 16 + lr][lg * 8];
    for (int n = 0; n < 4; n++) bfm[n] = *(const bf16x8*)&Bs[wc * 64 + n * 16 + lr][lg * 8];
    for (int m = 0; m < 4; m++)
      for (int n = 0; n < 4; n++)
        acc[m][n] = mfma16(af[m], bfm[n], acc[m][n]);
    __syncthreads();
  }
  for (int m = 0; m < 4; m++)
    for (int n = 0; n < 4; n++) {
      int row = m0 + wr * 64 + m * 16 + lg * 4;
      int col = n0 + wc * 64 + n * 16 + lr;
      for (int r = 0; r < 4; r++) {
        float v = acc[m][n][r];
        if constexpr (sizeof(OutT) == 2)
          Co[(size_t)(row + r) * N + col] = __float2bfloat16(v);
        else
          Co[(size_t)(row + r) * N + col] = v;
      }
    }
}

// ---------------- in-place QK RMSNorm over head dim (D=128) ----------------
// One wave per head-vector. Q gets 1/sqrt(D) folded in.
__global__ __launch_bounds__(256) void k_qkrms(__hip_bfloat16* __restrict__ QKV,
    const float* __restrict__ qw, const float* __restrict__ kw) {
  int bt = blockIdx.x;
  int w = threadIdx.x >> 6, lane = threadIdx.x & 63;
  int hv = blockIdx.y * 4 + w;
  const float* wt; int col; float extra;
  if (hv < 16) { wt = qw; col = hv * Dc;             extra = QSCALE; }
  else         { wt = kw; col = Cc + (hv - 16) * Dc; extra = 1.0f;   }
  __hip_bfloat16* p = QKV + (size_t)bt * NQ + col + lane * 2;
  float x0 = __bfloat162float(p[0]);
  float x1 = __bfloat162float(p[1]);
  float ss = x0 * x0 + x1 * x1;
  for (int m = 1; m < 64; m <<= 1) ss += __shfl_xor(ss, m);
  float sc = rsqrtf(ss * (1.0f / Dc) + EPSc) * extra;
  p[0] = __float2bfloat16(x0 * sc * wt[lane * 2]);
  p[1] = __float2bfloat16(x1 * sc * wt[lane * 2 + 1]);
}

// ---------------- V transpose: (b,t,h,d) cols of QKV -> Vt (b,h,d,t) -------
__global__ __launch_bounds__(256) void k_vtrans(const __hip_bfloat16* __restrict__ QKV,
                                                __hip_bfloat16* __restrict__ Vt) {
  __shared__ __hip_bfloat16 tile[64][65];
  int bh = blockIdx.z, t0 = blockIdx.x * 64, d0 = blockIdx.y * 64;
  int b = bh >> 4, h = bh & 15;
  int c = threadIdx.x & 63, rb = threadIdx.x >> 6;
  for (int i = 0; i < 16; i++) {
    int r = rb * 16 + i;
    tile[r][c] = QKV[(size_t)(b * Tc + t0 + r) * NQ + 2 * Cc + h * Dc + d0 + c];
  }
  __syncthreads();
  for (int i = 0; i < 16; i++) {
    int r = rb * 16 + i;
    Vt[((size_t)bh * Dc + d0 + r) * Tc + t0 + c] = tile[c][r];
  }
}

// ---------------- flash attention + ALiBi + causal + fused subln ----------
// grid (T/64, B*H); 4 waves; wave w owns q rows [qt*64+w*16, +16)
__global__ __launch_bounds__(256) void k_attn(const __hip_bfloat16* __restrict__ QKV,
    const __hip_bfloat16* __restrict__ Vt, const float* __restrict__ subw,
    __hip_bfloat16* __restrict__ Y) {
  __shared__ __align__(16) __hip_bfloat16 Plds[4][16][32];
  const int qt = blockIdx.x, bh = blockIdx.y;
  const int b = bh >> 4, h = bh & 15;
  const int w = threadIdx.x >> 6, lane = threadIdx.x & 63;
  const int lr = lane & 15, lg = lane >> 4;
  const int q0 = qt * 64 + w * 16;
  const float slope = exp2f(-0.5f * (float)(h + 1));
  bf16x8 aq[4];
  {
    const __hip_bfloat16* qb = QKV + (size_t)(b * Tc + q0 + lr) * NQ + h * Dc + lg * 8;
    for (int c = 0; c < 4; c++) aq[c] = *(const bf16x8*)(qb + c * 32);
  }
  f32x4 zero = {0.f, 0.f, 0.f, 0.f};
  f32x4 acc[8];
  for (int d = 0; d < 8; d++) acc[d] = zero;
  float mrow[4] = {-1e30f, -1e30f, -1e30f, -1e30f};
  float lrow[4] = {0.f, 0.f, 0.f, 0.f};
  const __hip_bfloat16* kb = QKV + (size_t)b * Tc * NQ + Cc + h * Dc + lg * 8;
  const __hip_bfloat16* vb = Vt + (size_t)bh * Dc * Tc + lg * 8;
  for (int s0 = 0; s0 < q0 + 16; s0 += 32) {
    f32x4 s[2]; s[0] = zero; s[1] = zero;
    for (int c = 0; c < 4; c++) {
      bf16x8 k0f = *(const bf16x8*)(kb + (size_t)(s0 + lr) * NQ + c * 32);
      s[0] = mfma16(aq[c], k0f, s[0]);
      bf16x8 k1f = *(const bf16x8*)(kb + (size_t)(s0 + 16 + lr) * NQ + c * 32);
      s[1] = mfma16(aq[c], k1f, s[1]);
    }
    float p0[4], p1[4], mt[4];
    for (int r = 0; r < 4; r++) {
      int i = q0 + lg * 4 + r;
      int j0 = s0 + lr, j1 = s0 + 16 + lr;
      p0[r] = (j0 <= i) ? s[0][r] - slope * (float)(i - j0) : -1e30f;
      p1[r] = (j1 <= i) ? s[1][r] - slope * (float)(i - j1) : -1e30f;
      mt[r] = fmaxf(p0[r], p1[r]);
    }
    for (int msk = 1; msk < 16; msk <<= 1)
      for (int r = 0; r < 4; r++) mt[r] = fmaxf(mt[r], __shfl_xor(mt[r], msk));
    float corr[4], rs[4];
    for (int r = 0; r < 4; r++) {
      float mn = fmaxf(mrow[r], mt[r]);
      corr[r] = __expf(mrow[r] - mn);
      mrow[r] = mn;
      p0[r] = __expf(p0[r] - mn);
      p1[r] = __expf(p1[r] - mn);
      rs[r] = p0[r] + p1[r];
    }
    for (int msk = 1; msk < 16; msk <<= 1)
      for (int r = 0; r < 4; r++) rs[r] += __shfl_xor(rs[r], msk);
    for (int r = 0; r < 4; r++) lrow[r] = lrow[r] * corr[r] + rs[r];
    for (int d = 0; d < 8; d++)
      for (int r = 0; r < 4; r++) acc[d][r] *= corr[r];
    // P -> LDS (D-layout -> A-layout relayout), wave-private slice
    for (int r = 0; r < 4; r++) {
      Plds[w][lg * 4 + r][lr]      = __float2bfloat16(p0[r]);
      Plds[w][lg * 4 + r][16 + lr] = __float2bfloat16(p1[r]);
    }
    bf16x8 pa = *(const bf16x8*)&Plds[w][lr][lg * 8];
    for (int d = 0; d < 8; d++) {
      bf16x8 bv = *(const bf16x8*)(vb + (size_t)(d * 16 + lr) * Tc + s0);
      acc[d] = mfma16(pa, bv, acc[d]);
    }
  }
  // epilogue: o = acc/l, subln rmsnorm over D, write Y (bt, h*D+d) bf16
  float ss[4] = {0.f, 0.f, 0.f, 0.f};
  for (int r = 0; r < 4; r++) {
    float rl = 1.0f / lrow[r];
    for (int d = 0; d < 8; d++) {
      float o = acc[d][r] * rl;
      acc[d][r] = o;
      ss[r] += o * o;
    }
  }
  for (int msk = 1; msk < 16; msk <<= 1)
    for (int r = 0; r < 4; r++) ss[r] += __shfl_xor(ss[r], msk);
  float ms[4];
  for (int r = 0; r < 4; r++) ms[r] = rsqrtf(ss[r] * (1.0f / Dc) + EPSc);
  for (int d = 0; d < 8; d++) {
    float wv = subw[d * 16 + lr];
    for (int r = 0; r < 4; r++) {
      float y = acc[d][r] * ms[r] * wv;
      Y[(size_t)(b * Tc + q0 + lg * 4 + r) * Cc + h * Dc + d * 16 + lr] = __float2bfloat16(y);
    }
  }
}

extern "C" void kernel_launch(void* const* d_in, const int* in_sizes, int n_in,
                              void* d_out, int out_size, void* d_ws, size_t ws_size,
                              hipStream_t stream) {
  const float* x  = (const float*)d_in[0];
  const float* Wq = (const float*)d_in[1];
  const float* Wk = (const float*)d_in[2];
  const float* Wv = (const float*)d_in[3];
  const float* Wp = (const float*)d_in[4];
  const float* qw = (const float*)d_in[5];
  const float* kw = (const float*)d_in[6];
  const float* sw = (const float*)d_in[7];
  float* out = (float*)d_out;

  char* ws = (char*)d_ws;
  // workspace layout (bytes), 128 MiB total
  __hip_bfloat16* Xb    = (__hip_bfloat16*)(ws + 0);          // 16 MiB (4096x2048)
  __hip_bfloat16* Wqkv  = (__hip_bfloat16*)(ws + 16777216);   // 24 MiB (6144x2048, N-major)
  __hip_bfloat16* Wproj = (__hip_bfloat16*)(ws + 41943040);   //  8 MiB (2048x2048, N-major)
  __hip_bfloat16* QKV   = (__hip_bfloat16*)(ws + 50331648);   // 48 MiB (4096x6144)
  __hip_bfloat16* Vt    = (__hip_bfloat16*)(ws + 100663296);  // 16 MiB (b,h,d,t)
  __hip_bfloat16* Yb    = (__hip_bfloat16*)(ws + 117440512);  // 16 MiB (4096x2048)

  // 1. convert x -> bf16
  k_xconv<<<dim3((BTc * Cc) / 1024), 256, 0, stream>>>(x, Xb);
  // 2. transpose+convert weights
  k_wconv<<<dim3(32, 32, 4), 256, 0, stream>>>(Wq, Wk, Wv, Wp, Wqkv, Wproj);
  // 3. QKV = Xb @ [Wq|Wk|Wv]   (4096 x 6144 x 2048)
  k_gemm<__hip_bfloat16><<<dim3(BTc / 128, NQ / 128), 256, 0, stream>>>(
      Xb, Wqkv, QKV, BTc, NQ, Cc);
  // 4. in-place RMSNorm on Q,K head-vectors (Q gets 1/sqrt(D) folded)
  k_qkrms<<<dim3(BTc, 8), 256, 0, stream>>>(QKV, qw, kw);
  // 5. V -> (b,h,d,t)
  k_vtrans<<<dim3(Tc / 64, Dc / 64, Bc * Hc), 256, 0, stream>>>(QKV, Vt);
  // 6. flash attention + subln, writes Y (bt, h*D+d) bf16
  k_attn<<<dim3(Tc / 64, Bc * Hc), 256, 0, stream>>>(QKV, Vt, sw, Yb);
  // 7. out = Y @ Wproj  (4096 x 2048 x 2048), fp32 out
  k_gemm<float><<<dim3(BTc / 128, Cc / 128), 256, 0, stream>>>(
      Yb, Wproj, out, BTc, Cc, Cc);
}

// Round 2
// 330.018 us; speedup vs baseline: 2.0574x; 2.0574x over previous
//
#include <hip/hip_runtime.h>
#include <hip/hip_bf16.h>

// Problem constants
#define Bc 2
#define Tc 2048
#define Cc 2048
#define Hc 16
#define Dc 128
#define BTc 4096
#define NQ 6144            // 3*Cc
#define EPSc 1e-5f
#define QSCALE 0.08838834764831845f   // 1/sqrt(128)

typedef __attribute__((ext_vector_type(8))) short bf16x8;
typedef __attribute__((ext_vector_type(4))) short bf16x4;
typedef __attribute__((ext_vector_type(4))) float f32x4;

__device__ __forceinline__ f32x4 mfma16(bf16x8 a, bf16x8 b, f32x4 c) {
  return __builtin_amdgcn_mfma_f32_16x16x32_bf16(a, b, c, 0, 0, 0);
}

__device__ __forceinline__ void gload16(const void* g, void* l) {
  __builtin_amdgcn_global_load_lds(
      (const __attribute__((address_space(1))) void*)g,
      (__attribute__((address_space(3))) void*)l, 16, 0, 0);
}

// ---------------- fp32 -> bf16 convert (x) ----------------
__global__ __launch_bounds__(256) void k_xconv(const float* __restrict__ x,
                                               __hip_bfloat16* __restrict__ xb) {
  size_t i = ((size_t)blockIdx.x * 256 + threadIdx.x) * 4;
  float4 v = *(const float4*)(x + i);
  union { __hip_bfloat16 h[4]; bf16x4 v4; } u;
  u.h[0] = __float2bfloat16(v.x); u.h[1] = __float2bfloat16(v.y);
  u.h[2] = __float2bfloat16(v.z); u.h[3] = __float2bfloat16(v.w);
  *(bf16x4*)(xb + i) = u.v4;
}

// ------- weight transpose+convert: W (K x N) fp32 -> Wt (N x K) bf16 -------
__global__ __launch_bounds__(256) void k_wconv(const float* __restrict__ Wq,
    const float* __restrict__ Wk, const float* __restrict__ Wv,
    const float* __restrict__ Wp, __hip_bfloat16* __restrict__ Wqkv_t,
    __hip_bfloat16* __restrict__ Wproj_t) {
  __shared__ float tile[64][65];
  int z = blockIdx.z;
  const float* src = (z == 0) ? Wq : (z == 1) ? Wk : (z == 2) ? Wv : Wp;
  __hip_bfloat16* dst = (z < 3) ? (Wqkv_t + (size_t)z * Cc * Cc) : Wproj_t;
  int k0 = blockIdx.x * 64, n0 = blockIdx.y * 64;
  int c = threadIdx.x & 63, rb = threadIdx.x >> 6;
  for (int i = 0; i < 16; i++) {
    int r = rb * 16 + i;
    tile[r][c] = src[(size_t)(k0 + r) * Cc + n0 + c];
  }
  __syncthreads();
  for (int i = 0; i < 16; i++) {
    int r = rb * 16 + i;
    dst[(size_t)(n0 + r) * Cc + k0 + c] = __float2bfloat16(tile[c][r]);
  }
}

// ---------------- bf16 GEMM, B pre-transposed (N x K), m97 structure -------
template <typename OutT>
__global__ __launch_bounds__(256) void k_gemm(const __hip_bfloat16* __restrict__ A,
    const __hip_bfloat16* __restrict__ Bt, OutT* __restrict__ Co,
    int M, int N, int K) {
  __shared__ __align__(16) __hip_bfloat16 As[128][32];
  __shared__ __align__(16) __hip_bfloat16 Bs[128][32];
  const int m0 = blockIdx.x * 128, n0 = blockIdx.y * 128;
  const int w = threadIdx.x >> 6, lane = threadIdx.x & 63;
  const int wr = w >> 1, wc = w & 1;
  const int lr = lane & 15, lg = lane >> 4;
  const int srow = lane >> 2, scolE = (lane & 3) * 8;
  f32x4 zero = {0.f, 0.f, 0.f, 0.f};
  f32x4 acc[4][4];
  for (int m = 0; m < 4; m++)
    for (int n = 0; n < 4; n++) acc[m][n] = zero;
  for (int k0 = 0; k0 < K; k0 += 32) {
    for (int q = 0; q < 2; q++) {
      int row = w * 32 + q * 16 + srow;
      gload16(A  + (size_t)(m0 + row) * K + k0 + scolE, &As[w * 32 + q * 16][0]);
      gload16(Bt + (size_t)(n0 + row) * K + k0 + scolE, &Bs[w * 32 + q * 16][0]);
    }
    __syncthreads();
    bf16x8 af[4], bfm[4];
    for (int m = 0; m < 4; m++) af[m]  = *(const bf16x8*)&As[wr * 64 + m * 16 + lr][lg * 8];
    for (int n = 0; n < 4; n++) bfm[n] = *(const bf16x8*)&Bs[wc * 64 + n * 16 + lr][lg * 8];
    for (int m = 0; m < 4; m++)
      for (int n = 0; n < 4; n++)
        acc[m][n] = mfma16(af[m], bfm[n], acc[m][n]);
    __syncthreads();
  }
  for (int m = 0; m < 4; m++)
    for (int n = 0; n < 4; n++) {
      int row = m0 + wr * 64 + m * 16 + lg * 4;
      int col = n0 + wc * 64 + n * 16 + lr;
      for (int r = 0; r < 4; r++) {
        float v = acc[m][n][r];
        if constexpr (sizeof(OutT) == 2)
          Co[(size_t)(row + r) * N + col] = __float2bfloat16(v);
        else
          Co[(size_t)(row + r) * N + col] = v;
      }
    }
}

// ---------------- in-place QK RMSNorm over head dim (D=128) ----------------
__global__ __launch_bounds__(256) void k_qkrms(__hip_bfloat16* __restrict__ QKV,
    const float* __restrict__ qw, const float* __restrict__ kw) {
  int bt = blockIdx.x;
  int w = threadIdx.x >> 6, lane = threadIdx.x & 63;
  int hv = blockIdx.y * 4 + w;
  const float* wt; int col; float extra;
  if (hv < 16) { wt = qw; col = hv * Dc;             extra = QSCALE; }
  else         { wt = kw; col = Cc + (hv - 16) * Dc; extra = 1.0f;   }
  __hip_bfloat16* p = QKV + (size_t)bt * NQ + col + lane * 2;
  float x0 = __bfloat162float(p[0]);
  float x1 = __bfloat162float(p[1]);
  float ss = x0 * x0 + x1 * x1;
  for (int m = 1; m < 64; m <<= 1) ss += __shfl_xor(ss, m);
  float sc = rsqrtf(ss * (1.0f / Dc) + EPSc) * extra;
  p[0] = __float2bfloat16(x0 * sc * wt[lane * 2]);
  p[1] = __float2bfloat16(x1 * sc * wt[lane * 2 + 1]);
}

// ---------------- V transpose: (b,t,h,d) cols of QKV -> Vt (b,h,d,t) -------
__global__ __launch_bounds__(256) void k_vtrans(const __hip_bfloat16* __restrict__ QKV,
                                                __hip_bfloat16* __restrict__ Vt) {
  __shared__ __hip_bfloat16 tile[64][65];
  int bh = blockIdx.z, t0 = blockIdx.x * 64, d0 = blockIdx.y * 64;
  int b = bh >> 4, h = bh & 15;
  int c = threadIdx.x & 63, rb = threadIdx.x >> 6;
  for (int i = 0; i < 16; i++) {
    int r = rb * 16 + i;
    tile[r][c] = QKV[(size_t)(b * Tc + t0 + r) * NQ + 2 * Cc + h * Dc + d0 + c];
  }
  __syncthreads();
  for (int i = 0; i < 16; i++) {
    int r = rb * 16 + i;
    Vt[((size_t)bh * Dc + d0 + r) * Tc + t0 + c] = tile[c][r];
  }
}

// ---------------- flash attention v2: LDS-staged K/V, dbuf, paired tiles ---
// grid (bh=32, pp=16); 4 waves; block handles q-tiles {31-pp, pp} (64 rows each)
__global__ __launch_bounds__(256, 2) void k_attn(const __hip_bfloat16* __restrict__ QKV,
    const __hip_bfloat16* __restrict__ Vt, const float* __restrict__ subw,
    __hip_bfloat16* __restrict__ Y) {
  __shared__ __align__(16) __hip_bfloat16 Ks[2][64][128];   // 32 KB
  __shared__ __align__(16) __hip_bfloat16 Vs[2][128][64];   // 32 KB
  __shared__ __align__(16) __hip_bfloat16 Plds[4][16][72];  // 9 KB (padded stride 144B)
  const int bh = blockIdx.x, pp = blockIdx.y;
  const int b = bh >> 4, h = bh & 15;
  const int w = threadIdx.x >> 6, lane = threadIdx.x & 63;
  const int lr = lane & 15, lg = lane >> 4;
  const float slope = exp2f(-0.5f * (float)(h + 1));
  const __hip_bfloat16* Kbase = QKV + (size_t)b * Tc * NQ + Cc + h * Dc;
  const __hip_bfloat16* Vbase = Vt + (size_t)bh * Dc * Tc;
  // staging geometry (per lane)
  const int krow = (lane >> 4);          // + w*16 + j*4
  const int kcolb = ((lane & 15) << 4);
  const int vrow = (lane >> 3);          // + w*32 + j*8
  const int vcolb = ((lane & 7) << 4);
  f32x4 zero = {0.f, 0.f, 0.f, 0.f};

  int buf = 0;
  for (int ti = 0; ti < 2; ti++) {
    const int qt = (ti == 0) ? (31 - pp) : pp;
    const int q0 = qt * 64 + w * 16;
    const int nchunk = qt + 1;
    // Q fragments (rms-normed, 1/sqrt(D) folded)
    bf16x8 aq[4];
    {
      const __hip_bfloat16* qb = QKV + (size_t)(b * Tc + q0 + lr) * NQ + h * Dc + lg * 8;
      for (int c = 0; c < 4; c++) aq[c] = *(const bf16x8*)(qb + c * 32);
    }
    f32x4 acc[8];
    for (int d = 0; d < 8; d++) acc[d] = zero;
    float mrow[4] = {-1e30f, -1e30f, -1e30f, -1e30f};
    float lrow[4] = {0.f, 0.f, 0.f, 0.f};

#define STAGE(bb, t)                                                              \
    {                                                                             \
      const int s0_ = (t) * 64;                                                   \
      for (int j = 0; j < 4; j++) {                                               \
        int row = w * 16 + j * 4 + krow;                                          \
        int cb = kcolb ^ ((row & 7) << 4);                                        \
        gload16(Kbase + (size_t)(s0_ + row) * NQ + (cb >> 1),                     \
                &Ks[bb][w * 16 + j * 4][0]);                                      \
      }                                                                           \
      for (int j = 0; j < 4; j++) {                                               \
        int row = w * 32 + j * 8 + vrow;                                          \
        int cb = vcolb ^ ((row & 7) << 4);                                        \
        gload16(Vbase + (size_t)row * Tc + s0_ + (cb >> 1),                       \
                &Vs[bb][w * 32 + j * 8][0]);                                      \
      }                                                                           \
    }

    STAGE(buf, 0);
    __syncthreads();
    for (int t = 0; t < nchunk; t++) {
      if (t + 1 < nchunk) STAGE(buf ^ 1, t + 1);
      const int s0 = t * 64;
      // ---- QK^T (16 MFMA) ----
      f32x4 s[4];
      for (int ss = 0; ss < 4; ss++) s[ss] = zero;
      __builtin_amdgcn_s_setprio(1);
      for (int c = 0; c < 4; c++)
        for (int ss = 0; ss < 4; ss++) {
          int kr = ss * 16 + lr;
          const bf16x8 kf = *(const bf16x8*)
              &Ks[buf][kr][((c * 64 + lg * 16) ^ ((kr & 7) << 4)) >> 1];
          s[ss] = mfma16(aq[c], kf, s[ss]);
        }
      __builtin_amdgcn_s_setprio(0);
      // ---- softmax (online) ----
      float ps[4][4], mt[4];
      for (int r = 0; r < 4; r++) mt[r] = -1e30f;
      for (int ss = 0; ss < 4; ss++) {
        int jj = s0 + ss * 16 + lr;
        for (int r = 0; r < 4; r++) {
          int i = q0 + lg * 4 + r;
          float pv = (jj <= i) ? s[ss][r] - slope * (float)(i - jj) : -1e30f;
          ps[ss][r] = pv;
          mt[r] = fmaxf(mt[r], pv);
        }
      }
      for (int m = 1; m < 16; m <<= 1)
        for (int r = 0; r < 4; r++) mt[r] = fmaxf(mt[r], __shfl_xor(mt[r], m));
      float corr[4], rs[4];
      for (int r = 0; r < 4; r++) {
        float mn = fmaxf(mrow[r], mt[r]);
        corr[r] = __expf(mrow[r] - mn);
        mrow[r] = mn;
        rs[r] = 0.f;
      }
      for (int ss = 0; ss < 4; ss++)
        for (int r = 0; r < 4; r++) {
          float e = __expf(ps[ss][r] - mrow[r]);
          ps[ss][r] = e;
          rs[r] += e;
        }
      for (int m = 1; m < 16; m <<= 1)
        for (int r = 0; r < 4; r++) rs[r] += __shfl_xor(rs[r], m);
      for (int r = 0; r < 4; r++) lrow[r] = lrow[r] * corr[r] + rs[r];
      for (int d = 0; d < 8; d++)
        for (int r = 0; r < 4; r++) acc[d][r] *= corr[r];
      // ---- P -> LDS (layout change), then PV (16 MFMA) ----
      for (int ss = 0; ss < 4; ss++)
        for (int r = 0; r < 4; r++)
          Plds[w][lg * 4 + r][ss * 16 + lr] = __float2bfloat16(ps[ss][r]);
      bf16x8 pa0 = *(const bf16x8*)&Plds[w][lr][lg * 8];
      bf16x8 pa1 = *(const bf16x8*)&Plds[w][lr][32 + lg * 8];
      __builtin_amdgcn_s_setprio(1);
      for (int d = 0; d < 8; d++) {
        int vr = d * 16 + lr;
        const bf16x8 b0 = *(const bf16x8*)
            &Vs[buf][vr][((lg * 16) ^ ((vr & 7) << 4)) >> 1];
        const bf16x8 b1 = *(const bf16x8*)
            &Vs[buf][vr][((64 + lg * 16) ^ ((vr & 7) << 4)) >> 1];
        acc[d] = mfma16(pa0, b0, acc[d]);
        acc[d] = mfma16(pa1, b1, acc[d]);
      }
      __builtin_amdgcn_s_setprio(0);
      __syncthreads();
      buf ^= 1;
    }
#undef STAGE
    // ---- epilogue: 1/l, subln rmsnorm, store ----
    float ssum[4] = {0.f, 0.f, 0.f, 0.f};
    for (int r = 0; r < 4; r++) {
      float rl = 1.0f / lrow[r];
      for (int d = 0; d < 8; d++) {
        float o = acc[d][r] * rl;
        acc[d][r] = o;
        ssum[r] += o * o;
      }
    }
    for (int m = 1; m < 16; m <<= 1)
      for (int r = 0; r < 4; r++) ssum[r] += __shfl_xor(ssum[r], m);
    float ms[4];
    for (int r = 0; r < 4; r++) ms[r] = rsqrtf(ssum[r] * (1.0f / Dc) + EPSc);
    for (int d = 0; d < 8; d++) {
      float wv = subw[d * 16 + lr];
      for (int r = 0; r < 4; r++) {
        float y = acc[d][r] * ms[r] * wv;
        Y[(size_t)(b * Tc + q0 + lg * 4 + r) * Cc + h * Dc + d * 16 + lr] =
            __float2bfloat16(y);
      }
    }
  }
}

extern "C" void kernel_launch(void* const* d_in, const int* in_sizes, int n_in,
                              void* d_out, int out_size, void* d_ws, size_t ws_size,
                              hipStream_t stream) {
  const float* x  = (const float*)d_in[0];
  const float* Wq = (const float*)d_in[1];
  const float* Wk = (const float*)d_in[2];
  const float* Wv = (const float*)d_in[3];
  const float* Wp = (const float*)d_in[4];
  const float* qw = (const float*)d_in[5];
  const float* kw = (const float*)d_in[6];
  const float* sw = (const float*)d_in[7];
  float* out = (float*)d_out;

  char* ws = (char*)d_ws;
  __hip_bfloat16* Xb    = (__hip_bfloat16*)(ws + 0);          // 16 MiB (4096x2048)
  __hip_bfloat16* Wqkv  = (__hip_bfloat16*)(ws + 16777216);   // 24 MiB (6144x2048, N-major)
  __hip_bfloat16* Wproj = (__hip_bfloat16*)(ws + 41943040);   //  8 MiB (2048x2048, N-major)
  __hip_bfloat16* QKV   = (__hip_bfloat16*)(ws + 50331648);   // 48 MiB (4096x6144)
  __hip_bfloat16* Vt    = (__hip_bfloat16*)(ws + 100663296);  // 16 MiB (b,h,d,t)
  __hip_bfloat16* Yb    = (__hip_bfloat16*)(ws + 117440512);  // 16 MiB (4096x2048)

  k_xconv<<<dim3((BTc * Cc) / 1024), 256, 0, stream>>>(x, Xb);
  k_wconv<<<dim3(32, 32, 4), 256, 0, stream>>>(Wq, Wk, Wv, Wp, Wqkv, Wproj);
  k_gemm<__hip_bfloat16><<<dim3(BTc / 128, NQ / 128), 256, 0, stream>>>(
      Xb, Wqkv, QKV, BTc, NQ, Cc);
  k_qkrms<<<dim3(BTc, 8), 256, 0, stream>>>(QKV, qw, kw);
  k_vtrans<<<dim3(Tc / 64, Dc / 64, Bc * Hc), 256, 0, stream>>>(QKV, Vt);
  k_attn<<<dim3(Bc * Hc, 16), 256, 0, stream>>>(QKV, Vt, sw, Yb);
  k_gemm<float><<<dim3(BTc / 128, Cc / 128), 256, 0, stream>>>(
      Yb, Wproj, out, BTc, Cc, Cc);
}